// Round 16
// baseline (248.700 us; speedup 1.0000x reference)
//
#include <hip/hip_runtime.h>
#include <cmath>
#include <cstddef>
#include <cstdint>

// Problem constants
#define BN   8
#define SN   1024
#define DMN  512
#define HN   8
#define DKN  64
#define DFFN 2048

typedef short           bf16x8   __attribute__((ext_vector_type(8)));
typedef float           f32x4    __attribute__((ext_vector_type(4)));
typedef float           f32x16   __attribute__((ext_vector_type(16)));
typedef unsigned short  ushortx4 __attribute__((ext_vector_type(4)));
typedef unsigned short  ushortx8 __attribute__((ext_vector_type(8)));
typedef unsigned int    uintx4   __attribute__((ext_vector_type(4)));
typedef unsigned short  u16;
typedef unsigned int    u32;

#define ATT_SC 0.18033688011112042f   // 0.125 * log2(e): folded into Q projection

__device__ __forceinline__ float bf2f(u16 u) {
  return __uint_as_float(((unsigned int)u) << 16);
}
__device__ __forceinline__ u16 f2bf(float f) {
  unsigned int u = __float_as_uint(f);
  u += 0x7FFFu + ((u >> 16) & 1u);          // RNE
  return (u16)(u >> 16);
}
__device__ __forceinline__ u32 cvtpk_bf16(float lo, float hi) {
  u32 r;
  asm("v_cvt_pk_bf16_f32 %0, %1, %2" : "=v"(r) : "v"(lo), "v"(hi));
  return r;
}
__device__ __forceinline__ void gload_lds16(const u16* gsrc, u16* ldst) {
  __builtin_amdgcn_global_load_lds(
      (const __attribute__((address_space(1))) unsigned int*)gsrc,
      (__attribute__((address_space(3))) unsigned int*)ldst,
      16, 0, 0);
}
// T1: XCD-aware bijective remap of a linear block id (requires nwg % 8 == 0).
__device__ __forceinline__ int xcd_swz(int lid, int nwg) {
  const int cpx = nwg >> 3;
  return (lid & 7) * cpx + (lid >> 3);
}

// ---------------- weight fp32 -> bf16 conversion ----------------
__global__ __launch_bounds__(256) void cvt_weights(
    const float* p0, const float* p1, const float* p2, const float* p3,
    const float* p4, const float* p5, const float* p6, const float* p7,
    const float* p8, const float* p9, u16* __restrict__ dst) {
  const int gi = blockIdx.x * 256 + threadIdx.x;   // group of 4 elems
  const int idx = gi * 4;
  const float* src; int off;
  if (idx < 2097152) {
    const int t = idx >> 18; off = idx & 262143;
    switch (t) {
      case 0: src = p0; break; case 1: src = p1; break;
      case 2: src = p2; break; case 3: src = p3; break;
      case 4: src = p4; break; case 5: src = p5; break;
      case 6: src = p6; break; default: src = p7; break;
    }
  } else if (idx < 3145728) { src = p8; off = idx - 2097152; }
  else                      { src = p9; off = idx - 3145728; }
  float4 v = *(const float4*)(src + off);
  ushortx4 o;
  o[0] = f2bf(v.x); o[1] = f2bf(v.y); o[2] = f2bf(v.z); o[3] = f2bf(v.w);
  *(ushortx4*)(dst + idx) = o;
}

// ---------------- bias packing for fused GEMMs ----------------
__global__ __launch_bounds__(256) void pack_bias(const float* a, const float* b,
                                                 const float* c, const float* d,
                                                 const float* e, float* __restrict__ dst) {
  const int t = threadIdx.x;
#pragma unroll
  for (int i = t; i < 512; i += 256) {
    dst[i]        = a[i];
    dst[512 + i]  = b[i];
    dst[1024 + i] = c[i];
    dst[1536 + i] = d[i];
    dst[2048 + i] = e[i];
  }
}

// ---------------- Global LayerNorm (two-pass), bf16 out ----------------
template<bool INBF>
__device__ __forceinline__ void ln_sum_body(const void* Xv_, float2* part, int g, int b, int t) {
  float s = 0.f, s2 = 0.f;
  if (INBF) {
    const ushortx8* Xv = (const ushortx8*)((const u16*)Xv_ + (size_t)b * (SN * DMN) + (size_t)g * 8192);
#pragma unroll
    for (int it = 0; it < 4; ++it) {
      ushortx8 x = Xv[t + it * 256];
#pragma unroll
      for (int e = 0; e < 8; ++e) { float f = bf2f(x[e]); s += f; s2 += f * f; }
    }
  } else {
    const float4* Xv = (const float4*)((const float*)Xv_ + (size_t)b * (SN * DMN) + (size_t)g * 8192);
#pragma unroll
    for (int it = 0; it < 8; ++it) {
      float4 x = Xv[t + it * 256];
      s  += x.x + x.y + x.z + x.w;
      s2 += x.x*x.x + x.y*x.y + x.z*x.z + x.w*x.w;
    }
  }
  __shared__ float rs[256], rq[256];
  rs[t] = s; rq[t] = s2;
  __syncthreads();
  for (int off = 128; off > 0; off >>= 1) {
    if (t < off) { rs[t] += rs[t + off]; rq[t] += rq[t + off]; }
    __syncthreads();
  }
  if (t == 0) part[b * 64 + g] = make_float2(rs[0], rq[0]);
}

template<bool INBF>
__device__ __forceinline__ void ln_norm_body(const void* Xv_, const float2* part,
                                             u16* Y, int g, int b, int t) {
  __shared__ float ss[64], sq[64];
  if (t < 64) { float2 p = part[b * 64 + t]; ss[t] = p.x; sq[t] = p.y; }
  __syncthreads();
  float s = 0.f, q = 0.f;
#pragma unroll
  for (int j = 0; j < 64; ++j) { s += ss[j]; q += sq[j]; }
  const float inv_n = 1.f / (float)(SN * DMN);
  const float mu = s * inv_n;
  const float var = q * inv_n - mu * mu;
  const float rstd = rsqrtf(var + 1e-5f);
  const size_t base = (size_t)b * (SN * DMN) + (size_t)g * 8192;
  if (INBF) {
    const ushortx8* Xv = (const ushortx8*)((const u16*)Xv_ + base);
#pragma unroll
    for (int it = 0; it < 4; ++it) {
      ushortx8 x = Xv[t + it * 256];
      ushortx8 o;
#pragma unroll
      for (int e = 0; e < 8; ++e) o[e] = f2bf((bf2f(x[e]) - mu) * rstd);
      *(ushortx8*)(Y + base + (size_t)(t + it * 256) * 8) = o;
    }
  } else {
    const float4* Xv = (const float4*)((const float*)Xv_ + base);
#pragma unroll
    for (int it = 0; it < 8; ++it) {
      float4 x = Xv[t + it * 256];
      ushortx4 o;
      o[0] = f2bf((x.x - mu) * rstd); o[1] = f2bf((x.y - mu) * rstd);
      o[2] = f2bf((x.z - mu) * rstd); o[3] = f2bf((x.w - mu) * rstd);
      *(ushortx4*)(Y + base + (size_t)(t + it * 256) * 4) = o;
    }
  }
}

template<bool INBF>
__global__ __launch_bounds__(256) void ln_sum(const void* __restrict__ Xv_,
                                              float2* __restrict__ part) {
  ln_sum_body<INBF>(Xv_, part, blockIdx.x, blockIdx.y, threadIdx.x);
}
template<bool INBF>
__global__ __launch_bounds__(256) void ln_norm(const void* __restrict__ Xv_,
                                               const float2* __restrict__ part,
                                               u16* __restrict__ Y) {
  ln_norm_body<INBF>(Xv_, part, Y, blockIdx.x, blockIdx.y, threadIdx.x);
}
// fused pair: z=0 bf16 src0, z=1 fp32 src1
__global__ __launch_bounds__(256) void ln_sum2(const void* __restrict__ X0,
                                               const void* __restrict__ X1,
                                               float2* __restrict__ part) {
  if (blockIdx.z == 0) ln_sum_body<true>(X0, part, blockIdx.x, blockIdx.y, threadIdx.x);
  else                 ln_sum_body<false>(X1, part + 512, blockIdx.x, blockIdx.y, threadIdx.x);
}
__global__ __launch_bounds__(256) void ln_norm2(const void* __restrict__ X0,
                                                const void* __restrict__ X1,
                                                const float2* __restrict__ part,
                                                u16* __restrict__ Y0,
                                                u16* __restrict__ Y1) {
  if (blockIdx.z == 0) ln_norm_body<true>(X0, part, Y0, blockIdx.x, blockIdx.y, threadIdx.x);
  else                 ln_norm_body<false>(X1, part + 512, Y1, blockIdx.x, blockIdx.y, threadIdx.x);
}

// ---------------- bf16 MFMA GEMM (BM x 128 tile, BK=64, 4 waves) ----------------
// BK=64 + global-source swizzle (slot ^= row&7), linear global_load_lds dest,
// matching XOR on fragment reads. DBUF: 2-phase double-buffer (one barrier/tile).
// BM in {32, 64, 128}. OMODE: 0 = fp32 out; 1 = bf16 out; 3 = QKV fused; 4 = KV
// fused. V output (seg_vt) is written in the PERMUTED slab layout that attention
// consumes directly. RESBF: residual is bf16. QSC: scale by ATT_SC (OMODE 3: Q seg).
template<bool RELU, bool RES, bool RESBF, int OMODE, int BM, bool QSC, bool DBUF>
__global__ __launch_bounds__(256) void gemm_mfma(const u16* __restrict__ A,
                                                 const u16* __restrict__ W,
                                                 const float* __restrict__ bias,
                                                 const void* __restrict__ resv,
                                                 void* __restrict__ Cv,
                                                 void* __restrict__ Cv2,
                                                 void* __restrict__ Cv3,
                                                 int M, int N, int K) {
  constexpr int MI = BM / 32;        // row-frags per wave (128->4, 64->2, 32->1)
  constexpr int NB = DBUF ? 2 : 1;
  __shared__ u16 As[NB][BM * 64];
  __shared__ u16 Bs[NB][128 * 64];
  const int t = threadIdx.x;
  const int lane = t & 63, w = t >> 6;
  const int wm = w >> 1, wn = w & 1;

  // T1 XCD swizzle
  const int gx = gridDim.x;
  const int lid = xcd_swz(blockIdx.y * gx + blockIdx.x, gx * gridDim.y);
  const int m0 = (lid / gx) * BM, n0 = (lid % gx) * 128;

  f32x4 acc[MI][4];
#pragma unroll
  for (int i = 0; i < MI; ++i)
#pragma unroll
    for (int j = 0; j < 4; ++j)
      acc[i][j] = (f32x4){0.f, 0.f, 0.f, 0.f};

  // staging: each round covers 32 rows (4 waves x 8 rows); thread handles 16B.
  const int srow = lane >> 3;                              // 0..7 in wave chunk
  const int scol = ((lane & 7) ^ (lane >> 3)) * 8;         // swizzled src col (elems)
  const int l15 = lane & 15, l4q = lane >> 4, l7 = lane & 7;

  auto STAGE = [&](int buf, int k0) {
#pragma unroll
    for (int c = 0; c < BM / 32; ++c) {
      const int r0 = c * 32 + w * 8;
      gload_lds16(A + (size_t)(m0 + r0 + srow) * K + k0 + scol, &As[buf][r0 * 64]);
    }
#pragma unroll
    for (int c = 0; c < 4; ++c) {
      const int r0 = c * 32 + w * 8;
      gload_lds16(W + (size_t)(n0 + r0 + srow) * K + k0 + scol, &Bs[buf][r0 * 64]);
    }
  };
  auto COMPUTE = [&](int buf) {
#pragma unroll
    for (int ks = 0; ks < 2; ++ks) {
      const int kofs = ((ks * 4 + l4q) ^ l7) * 8;          // swizzled read slot
      bf16x8 af[MI], bfr[4];
#pragma unroll
      for (int f = 0; f < MI; ++f)
        af[f]  = *(const bf16x8*)&As[buf][(wm * (BM / 2) + f * 16 + l15) * 64 + kofs];
#pragma unroll
      for (int f = 0; f < 4; ++f)
        bfr[f] = *(const bf16x8*)&Bs[buf][(wn * 64 + f * 16 + l15) * 64 + kofs];
#pragma unroll
      for (int i = 0; i < MI; ++i)
#pragma unroll
        for (int j = 0; j < 4; ++j)
          acc[i][j] = __builtin_amdgcn_mfma_f32_16x16x32_bf16(af[i], bfr[j], acc[i][j], 0, 0, 0);
    }
  };

  if (DBUF) {
    const int nt = K >> 6;
    STAGE(0, 0);
    __syncthreads();                       // drains prologue loads
    for (int ti = 0; ti < nt; ++ti) {
      if (ti + 1 < nt) STAGE((ti + 1) & 1, (ti + 1) << 6);
      COMPUTE(ti & 1);
      if (ti + 1 < nt) __syncthreads();    // drains STAGE(ti+1); protects buf reuse
    }
  } else {
    for (int k0 = 0; k0 < K; k0 += 64) {
      STAGE(0, k0);
      __syncthreads();
      COMPUTE(0);
      __syncthreads();
    }
  }

  const int crow0 = (lane >> 4) * 4;
  const int ccol  = lane & 15;
  float bv[4];
#pragma unroll
  for (int j = 0; j < 4; ++j) bv[j] = bias[n0 + wn * 64 + j * 16 + ccol];

  u16* seg_out = nullptr;
  int  seg_n0 = 0;
  bool seg_vt = false;
  if (OMODE == 3) {
    if (n0 < 512)       { seg_out = (u16*)Cv;  seg_n0 = 0; }
    else if (n0 < 1024) { seg_out = (u16*)Cv2; seg_n0 = 512; }
    else                { seg_out = (u16*)Cv3; seg_n0 = 1024; seg_vt = true; }
  } else if (OMODE == 4) {
    if (n0 < 512)       { seg_out = (u16*)Cv;  seg_n0 = 0; }
    else                { seg_out = (u16*)Cv3; seg_n0 = 512; seg_vt = true; }
  }
  const bool do_scale = QSC && (OMODE != 3 || n0 < 512);

#pragma unroll
  for (int i = 0; i < MI; ++i) {
#pragma unroll
    for (int r = 0; r < 4; ++r) {
      const int m = m0 + wm * (BM / 2) + i * 16 + crow0 + r;
#pragma unroll
      for (int j = 0; j < 4; ++j) {
        const int n = n0 + wn * 64 + j * 16 + ccol;
        float v = acc[i][j][r] + bv[j];
        if (RELU) v = fmaxf(v, 0.f);
        if (RES) {
          if (RESBF) v += bf2f(((const u16*)resv)[(size_t)m * N + n]);
          else       v += ((const float*)resv)[(size_t)m * N + n];
        }
        if (do_scale) v *= ATT_SC;
        if (OMODE == 0) {
          ((float*)Cv)[(size_t)m * N + n] = v;
        } else if (OMODE == 1) {
          ((u16*)Cv)[(size_t)m * N + n] = f2bf(v);
        } else {
          const int nn = n - seg_n0;
          if (!seg_vt) {
            seg_out[(size_t)m * 512 + nn] = f2bf(v);
          } else {
            // permuted V slab layout (consumed directly by attn staging)
            const int s_ = m & 1023, k_ = s_ & 63;
            const int slab = 4 * (k_ >> 5) + 2 * ((k_ >> 4) & 1) + ((k_ >> 2) & 1);
            const int jj   = 4 * ((k_ >> 3) & 1) + (k_ & 3);
            seg_out[(((((size_t)(m >> 10) * HN + (nn >> 6)) * 16 + (s_ >> 6)) * 8 + slab) * 64
                     + (nn & 63)) * 8 + jj] = f2bf(v);
          }
        }
      }
    }
  }
}

// ---------------- MFMA flash attention: swapped 32x32, fixed-max exp2 softmax ----
// Double-buffered K/V LDS, ONE barrier per tile. V pre-permuted in slab layout.
// PV accumulators split even/odd-m into independent chains (a/b), merged in the
// epilogue — halves the MFMA RAW-dependency depth per tile at zero per-tile cost.
// NSPLIT==1: normalized O out. NSPLIT==2: raw acc + l, exact-add merge.
#define QBLK 128
#define KVB  64

template<int CAUSAL, int NSPLIT>
__global__ __launch_bounds__(256) void attn_mfma(const u16* __restrict__ Q,
                                                 const u16* __restrict__ K,
                                                 const u16* __restrict__ VTp,
                                                 u16* __restrict__ Out,
                                                 float* __restrict__ Lbuf) {
  const int lid = xcd_swz(blockIdx.y * 8 + blockIdx.x, 512);
  const int qb = lid & 7;                 // 0..7
  const int bh = lid >> 3;
  const int sp = (NSPLIT > 1) ? blockIdx.z : 0;
  const int b = bh >> 3, h = bh & 7;
  const int t = threadIdx.x;
  const int lane = t & 63, w = t >> 6;
  const int l31 = lane & 31, hi = lane >> 5;

  __shared__ __align__(16) u16 Ks[2][64 * 64];
  __shared__ __align__(16) u16 Vts[2][8 * 512];

  const int qw0 = qb * QBLK + w * 32;     // wave's first q row
  const int qglob = qw0 + l31;            // this lane's q row

  // Q B-frags (already scaled at projection)
  bf16x8 bq[4];
#pragma unroll
  for (int dk = 0; dk < 4; ++dk)
    bq[dk] = *(const bf16x8*)(Q + (size_t)(b * SN + qglob) * 512
                                + h * 64 + dk * 16 + hi * 8);

  // O accum: D[d][q]; split into two independent chains (even/odd m)
  f32x16 acc0a = {}, acc0b = {}, acc1a = {}, acc1b = {};
  float l_run = 0.f;                      // lane-local half-sum

  const int ntile = CAUSAL ? (2 * qb + 2) : (SN / KVB);
  const int n4 = (ntile + NSPLIT - 1) / NSPLIT;
  const int kt0 = sp * n4;
  const int ktend = (kt0 + n4 < ntile) ? (kt0 + n4) : ntile;
  const int ntk = ktend - kt0;            // block-uniform

  // staging maps
  const int srow = t >> 2;                // K row 0..63
  const int ss0  = 2 * (t & 3);           // 16B slot (0,2,4,6)
  const u16* kg0 = K + (size_t)(b * SN + srow) * 512 + h * 64 + ((ss0 ^ (srow & 7)) * 8)
                     + (size_t)kt0 * KVB * 512;
  const u16* kg1 = K + (size_t)(b * SN + srow) * 512 + h * 64 + (((ss0 + 1) ^ (srow & 7)) * 8)
                     + (size_t)kt0 * KVB * 512;
  const int vd = t & 63, vp = t >> 6;
  const u16* vg = VTp + (((size_t)bh * 16 + kt0) * 8 + 2 * vp) * 512 + vd * 8;

  ushortx8 kr0, kr1, vr0, vr1;
  auto LOADREGS = [&]() {
    kr0 = *(const ushortx8*)kg0;
    kr1 = *(const ushortx8*)kg1;
    vr0 = *(const ushortx8*)vg;
    vr1 = *(const ushortx8*)(vg + 512);
    kg0 += (size_t)KVB * 512; kg1 += (size_t)KVB * 512; vg += 4096;
  };
  auto WRITELDS = [&](int buf) {
    *(ushortx8*)&Ks[buf][t * 16]     = kr0;
    *(ushortx8*)&Ks[buf][t * 16 + 8] = kr1;
    *(ushortx8*)&Vts[buf][(2 * vp) * 512 + vd * 8]     = vr0;
    *(ushortx8*)&Vts[buf][(2 * vp + 1) * 512 + vd * 8] = vr1;
  };

  // prologue: tile0 -> buf0; prefetch tile1 regs
  LOADREGS();
  WRITELDS(0);
  if (ntk > 1) LOADREGS();
  __syncthreads();

  for (int ti = 0; ti < ntk; ++ti) {
    const int kt = kt0 + ti;
    const int k0 = kt * KVB;
    const int cur = ti & 1;
    if (ti + 1 < ntk) {
      WRITELDS(cur ^ 1);                   // regs hold tile ti+1
      if (ti + 2 < ntk) LOADREGS();        // issue tile ti+2
    }

    if (!(CAUSAL && k0 > qw0 + 31)) {
      // ---- QK^T swapped: D[k][q], accumulate over 4 dk slices ----
      f32x16 s0 = {}, s1 = {};
      __builtin_amdgcn_s_setprio(1);
#pragma unroll
      for (int dk = 0; dk < 4; ++dk) {
        const int boff = dk * 32 + hi * 16;               // byte offset in 128B row
        const int sw = boff ^ ((l31 & 7) << 4);
        bf16x8 a0 = *(const bf16x8*)&Ks[cur][l31 * 64 + (sw >> 1)];
        bf16x8 a1 = *(const bf16x8*)&Ks[cur][(32 + l31) * 64 + (sw >> 1)];
        s0 = __builtin_amdgcn_mfma_f32_32x32x16_bf16(a0, bq[dk], s0, 0, 0, 0);
        s1 = __builtin_amdgcn_mfma_f32_32x32x16_bf16(a1, bq[dk], s1, 0, 0, 0);
      }
      __builtin_amdgcn_s_setprio(0);

      // ---- fixed-max softmax: P = exp2(s) ----
      if (CAUSAL && (k0 + KVB - 1 > qw0)) {
#pragma unroll
        for (int i = 0; i < 16; ++i) {
          const int krow = (i & 3) + 8 * (i >> 2) + 4 * hi;
          if (k0 + krow > qglob)      s0[i] = -INFINITY;
          if (k0 + 32 + krow > qglob) s1[i] = -INFINITY;
        }
      }
      float ps = 0.f;
#pragma unroll
      for (int i = 0; i < 16; ++i) {
        s0[i] = exp2f(s0[i]); ps += s0[i];
        s1[i] = exp2f(s1[i]); ps += s1[i];
      }
      l_run += ps;

      // ---- PV with permuted-k slabs; even/odd-m chains independent ----
      __builtin_amdgcn_s_setprio(1);
#pragma unroll
      for (int m = 0; m < 4; ++m) {
        uintx4 pw;
        if (m == 0) {
          pw[0] = cvtpk_bf16(s0[0], s0[1]);  pw[1] = cvtpk_bf16(s0[2], s0[3]);
          pw[2] = cvtpk_bf16(s0[4], s0[5]);  pw[3] = cvtpk_bf16(s0[6], s0[7]);
        } else if (m == 1) {
          pw[0] = cvtpk_bf16(s0[8], s0[9]);  pw[1] = cvtpk_bf16(s0[10], s0[11]);
          pw[2] = cvtpk_bf16(s0[12], s0[13]); pw[3] = cvtpk_bf16(s0[14], s0[15]);
        } else if (m == 2) {
          pw[0] = cvtpk_bf16(s1[0], s1[1]);  pw[1] = cvtpk_bf16(s1[2], s1[3]);
          pw[2] = cvtpk_bf16(s1[4], s1[5]);  pw[3] = cvtpk_bf16(s1[6], s1[7]);
        } else {
          pw[0] = cvtpk_bf16(s1[8], s1[9]);  pw[1] = cvtpk_bf16(s1[10], s1[11]);
          pw[2] = cvtpk_bf16(s1[12], s1[13]); pw[3] = cvtpk_bf16(s1[14], s1[15]);
        }
        const bf16x8 pb = *(const bf16x8*)&pw;
        const bf16x8 av0 = *(const bf16x8*)&Vts[cur][(m * 2 + hi) * 512 + l31 * 8];
        const bf16x8 av1 = *(const bf16x8*)&Vts[cur][(m * 2 + hi) * 512 + (32 + l31) * 8];
        if (m & 1) {
          acc0b = __builtin_amdgcn_mfma_f32_32x32x16_bf16(av0, pb, acc0b, 0, 0, 0);
          acc1b = __builtin_amdgcn_mfma_f32_32x32x16_bf16(av1, pb, acc1b, 0, 0, 0);
        } else {
          acc0a = __builtin_amdgcn_mfma_f32_32x32x16_bf16(av0, pb, acc0a, 0, 0, 0);
          acc1a = __builtin_amdgcn_mfma_f32_32x32x16_bf16(av1, pb, acc1a, 0, 0, 0);
        }
      }
      __builtin_amdgcn_s_setprio(0);
    }
    if (ti + 1 < ntk) __syncthreads();     // protects buf reuse next iter
  }

  // ---- epilogue: merge chains ----
  const f32x16 acc0 = acc0a + acc0b;
  const f32x16 acc1 = acc1a + acc1b;
  l_run += __shfl_xor(l_run, 32);         // combine lane halves (once)
  if (NSPLIT == 1) {
    const float inv = 1.f / l_run;
    u16* op = Out + (size_t)(b * SN + qglob) * 512 + h * 64;
#pragma unroll
    for (int g = 0; g < 4; ++g) {
      ushortx4 o0, o1;
#pragma unroll
      for (int r = 0; r < 4; ++r) {
        o0[r] = f2bf(acc0[4*g + r] * inv);
        o1[r] = f2bf(acc1[4*g + r] * inv);
      }
      *(ushortx4*)(op + 4*hi + 8*g)      = o0;
      *(ushortx4*)(op + 32 + 4*hi + 8*g) = o1;
    }
  } else {
    u16* op = Out + (((size_t)(sp * 64 + bh)) * 1024 + qglob) * 64;
#pragma unroll
    for (int g = 0; g < 4; ++g) {
      ushortx4 o0, o1;
#pragma unroll
      for (int r = 0; r < 4; ++r) {
        o0[r] = f2bf(acc0[4*g + r]);
        o1[r] = f2bf(acc1[4*g + r]);
      }
      *(ushortx4*)(op + 4*hi + 8*g)      = o0;
      *(ushortx4*)(op + 32 + 4*hi + 8*g) = o1;
    }
    if (hi == 0)
      Lbuf[((size_t)(sp * 64 + bh)) * 1024 + qglob] = l_run;
  }
}

// ---------------- 2-way split merge (fixed max -> exact addition) ----------------
__global__ __launch_bounds__(256) void attn_merge2(const u16* __restrict__ Pacc,
                                                   const float* __restrict__ Lbuf,
                                                   u16* __restrict__ O) {
  const int tid = blockIdx.x * 256 + threadIdx.x;   // 524288 threads
  const int qh = tid >> 3;
  const int d0 = (tid & 7) * 8;
  const int bh = qh >> 10, q = qh & 1023;
  const int b = bh >> 3, h = bh & 7;

  const float l = Lbuf[(size_t)bh * 1024 + q] + Lbuf[(size_t)(64 + bh) * 1024 + q];
  const float inv = 1.f / l;
  ushortx8 a0 = *(const ushortx8*)(Pacc + ((size_t)bh * 1024 + q) * 64 + d0);
  ushortx8 a1 = *(const ushortx8*)(Pacc + ((size_t)(64 + bh) * 1024 + q) * 64 + d0);
  ushortx8 ov;
#pragma unroll
  for (int e = 0; e < 8; ++e)
    ov[e] = f2bf((bf2f(a0[e]) + bf2f(a1[e])) * inv);
  *(ushortx8*)(O + ((size_t)(b * 1024 + q) * 512) + h * 64 + d0) = ov;
}

extern "C" void kernel_launch(void* const* d_in, const int* in_sizes, int n_in,
                              void* d_out, int out_size, void* d_ws, size_t ws_size,
                              hipStream_t stream) {
  const float* x_enc = (const float*)d_in[0];
  const float* x_dec = (const float*)d_in[1];
  const float* mq_w = (const float*)d_in[2];  const float* mq_b = (const float*)d_in[3];
  const float* mk_w = (const float*)d_in[4];  const float* mk_b = (const float*)d_in[5];
  const float* mv_w = (const float*)d_in[6];  const float* mv_b = (const float*)d_in[7];
  const float* mo_w = (const float*)d_in[8];  const float* mo_b = (const float*)d_in[9];
  const float* cq_w = (const float*)d_in[10]; const float* cq_b = (const float*)d_in[11];
  const float* ck_w = (const float*)d_in[12]; const float* ck_b = (const float*)d_in[13];
  const float* cv_w = (const float*)d_in[14]; const float* cv_b = (const float*)d_in[15];
  const float* co_w = (const float*)d_in[16]; const float* co_b = (const float*)d_in[17];
  const float* f1_w = (const float*)d_in[18]; const float* f1_b = (const float*)d_in[19];
  const float* f2_w = (const float*)d_in[20]; const float* f2_b = (const float*)d_in[21];
  float* out = (float*)d_out;

  // ---- workspace layout (bytes) ----
  char* wsb = (char*)d_ws;
  u16* o5    = (u16*)(wsb + 0);                   // current, bf16, 8 MB
  u16* o6    = (u16*)(wsb + (16u << 20));         // result,  bf16, 8 MB
  u16* Qb    = (u16*)(wsb + (32u << 20));         // 8 MB
  u16* Kb    = (u16*)(wsb + (40u << 20));         // 8 MB
  u16* VTb   = (u16*)(wsb + (48u << 20));         // 8 MB, permuted slab layout
  u16* B0    = (u16*)(wsb + (56u << 20));         // bf16 scratch, 8 MB
  u16* B1    = (u16*)(wsb + (64u << 20));         // enc_n bf16 / attn Lbuf
  u16* FF1   = (u16*)(wsb + (72u << 20));         // FF1 32MB / attn Pacc 16MB (disjoint phases)
  u16* WB    = (u16*)(wsb + (104u << 20));        // bf16 weights, 8 MB
  float2* part = (float2*)(wsb + (112u << 20));   // LN partials (1024 float2)
  float* BC  = (float*)(wsb + (113u << 20));      // packed biases (2560 floats)

  u16* Pacc   = FF1;                              // [2][64][1024][64] bf16
  float* Lbuf = (float*)B1;                       // [2][64][1024] float

  u16* wb_mq = WB + 0 * 262144;                   // qkv fused base
  u16* wb_mo = WB + 3 * 262144;
  u16* wb_cq = WB + 4 * 262144;
  u16* wb_ck = WB + 5 * 262144;                   // kv fused base
  u16* wb_co = WB + 7 * 262144;
  u16* wb_f1 = WB + 8 * 262144; u16* wb_f2 = WB + 8 * 262144 + 1048576;

  const int M = BN * SN;  // 8192
  dim3 ln_grid(64, BN);
  dim3 ln_grid2(64, BN, 2);
  dim3 g512t(512 / 128, M / 32);     // BM=32 for N=512 GEMMs: 1024 blocks
  dim3 gqkv(1536 / 128, M / 64);     // BM=64: 1536 blocks
  dim3 gkv(1024 / 128, M / 64);      // BM=64: 1024 blocks
  dim3 gff1(2048 / 128, M / 64);     // BM=64: 2048 blocks (was BM=128 @ 1024)
  dim3 attn_grid_c(SN / QBLK, BN * HN, 2);   // causal: 2-way KV split
  dim3 attn_grid_x(SN / QBLK, BN * HN, 1);   // cross: no split

  cvt_weights<<<4096, 256, 0, stream>>>(mq_w, mk_w, mv_w, mo_w, cq_w, ck_w, cv_w, co_w,
                                        f1_w, f2_w, WB);
  pack_bias<<<1, 256, 0, stream>>>(mq_b, mk_b, mv_b, ck_b, cv_b, BC);

  // ---- masked self-attention block ----
  ln_sum<false><<<ln_grid, 256, 0, stream>>>(x_dec, part);
  ln_norm<false><<<ln_grid, 256, 0, stream>>>(x_dec, part, B0);
  gemm_mfma<false, false, false, 3, 64, true, false><<<gqkv, 256, 0, stream>>>(
      B0, wb_mq, BC, nullptr, Qb, Kb, VTb, M, 1536, 512);
  attn_mfma<1, 2><<<attn_grid_c, 256, 0, stream>>>(Qb, Kb, VTb, Pacc, Lbuf);
  attn_merge2<<<2048, 256, 0, stream>>>(Pacc, Lbuf, B0);
  gemm_mfma<false, true, false, 1, 32, false, true><<<g512t, 256, 0, stream>>>(
      B0, wb_mo, mo_b, x_dec, o5, nullptr, nullptr, M, 512, 512);

  // ---- cross-attention block ----
  ln_sum2<<<ln_grid2, 256, 0, stream>>>(o5, x_enc, part);
  ln_norm2<<<ln_grid2, 256, 0, stream>>>(o5, x_enc, part, B0, B1);   // cur_n, enc_n
  gemm_mfma<false, false, false, 1, 32, true, true><<<g512t, 256, 0, stream>>>(
      B0, wb_cq, cq_b, nullptr, Qb, nullptr, nullptr, M, 512, 512);
  gemm_mfma<false, false, false, 4, 64, false, false><<<gkv, 256, 0, stream>>>(
      B1, wb_ck, BC + 1536, nullptr, Kb, nullptr, VTb, M, 1024, 512);
  attn_mfma<0, 1><<<attn_grid_x, 256, 0, stream>>>(Qb, Kb, VTb, B0, nullptr);
  gemm_mfma<false, true, true, 1, 32, false, true><<<g512t, 256, 0, stream>>>(
      B0, wb_co, co_b, o5, o6, nullptr, nullptr, M, 512, 512);

  // ---- feedforward block ----
  ln_sum<true><<<ln_grid, 256, 0, stream>>>(o6, part);
  ln_norm<true><<<ln_grid, 256, 0, stream>>>(o6, part, B0);      // res_n
  gemm_mfma<true, false, false, 1, 64, false, false><<<gff1, 256, 0, stream>>>(
      B0, wb_f1, f1_b, nullptr, FF1, nullptr, nullptr, M, 2048, 512);
  gemm_mfma<false, true, true, 0, 32, false, true><<<g512t, 256, 0, stream>>>(
      FF1, wb_f2, f2_b, o6, out, nullptr, nullptr, M, 512, 2048);
}

// Round 17
// 245.418 us; speedup vs baseline: 1.0134x; 1.0134x over previous
//
#include <hip/hip_runtime.h>
#include <cmath>
#include <cstddef>
#include <cstdint>

// Problem constants
#define BN   8
#define SN   1024
#define DMN  512
#define HN   8
#define DKN  64
#define DFFN 2048

typedef short           bf16x8   __attribute__((ext_vector_type(8)));
typedef float           f32x4    __attribute__((ext_vector_type(4)));
typedef float           f32x16   __attribute__((ext_vector_type(16)));
typedef unsigned short  ushortx4 __attribute__((ext_vector_type(4)));
typedef unsigned short  ushortx8 __attribute__((ext_vector_type(8)));
typedef unsigned int    uintx4   __attribute__((ext_vector_type(4)));
typedef unsigned short  u16;
typedef unsigned int    u32;

#define ATT_SC 0.18033688011112042f   // 0.125 * log2(e): folded into Q projection

__device__ __forceinline__ float bf2f(u16 u) {
  return __uint_as_float(((unsigned int)u) << 16);
}
__device__ __forceinline__ u16 f2bf(float f) {
  unsigned int u = __float_as_uint(f);
  u += 0x7FFFu + ((u >> 16) & 1u);          // RNE
  return (u16)(u >> 16);
}
__device__ __forceinline__ u32 cvtpk_bf16(float lo, float hi) {
  u32 r;
  asm("v_cvt_pk_bf16_f32 %0, %1, %2" : "=v"(r) : "v"(lo), "v"(hi));
  return r;
}
__device__ __forceinline__ void gload_lds16(const u16* gsrc, u16* ldst) {
  __builtin_amdgcn_global_load_lds(
      (const __attribute__((address_space(1))) unsigned int*)gsrc,
      (__attribute__((address_space(3))) unsigned int*)ldst,
      16, 0, 0);
}
// T1: XCD-aware bijective remap of a linear block id (requires nwg % 8 == 0).
__device__ __forceinline__ int xcd_swz(int lid, int nwg) {
  const int cpx = nwg >> 3;
  return (lid & 7) * cpx + (lid >> 3);
}

// ---------------- weight fp32 -> bf16 conversion ----------------
__global__ __launch_bounds__(256) void cvt_weights(
    const float* p0, const float* p1, const float* p2, const float* p3,
    const float* p4, const float* p5, const float* p6, const float* p7,
    const float* p8, const float* p9, u16* __restrict__ dst) {
  const int gi = blockIdx.x * 256 + threadIdx.x;   // group of 4 elems
  const int idx = gi * 4;
  const float* src; int off;
  if (idx < 2097152) {
    const int t = idx >> 18; off = idx & 262143;
    switch (t) {
      case 0: src = p0; break; case 1: src = p1; break;
      case 2: src = p2; break; case 3: src = p3; break;
      case 4: src = p4; break; case 5: src = p5; break;
      case 6: src = p6; break; default: src = p7; break;
    }
  } else if (idx < 3145728) { src = p8; off = idx - 2097152; }
  else                      { src = p9; off = idx - 3145728; }
  float4 v = *(const float4*)(src + off);
  ushortx4 o;
  o[0] = f2bf(v.x); o[1] = f2bf(v.y); o[2] = f2bf(v.z); o[3] = f2bf(v.w);
  *(ushortx4*)(dst + idx) = o;
}

// ---------------- bias packing for fused GEMMs ----------------
__global__ __launch_bounds__(256) void pack_bias(const float* a, const float* b,
                                                 const float* c, const float* d,
                                                 const float* e, float* __restrict__ dst) {
  const int t = threadIdx.x;
#pragma unroll
  for (int i = t; i < 512; i += 256) {
    dst[i]        = a[i];
    dst[512 + i]  = b[i];
    dst[1024 + i] = c[i];
    dst[1536 + i] = d[i];
    dst[2048 + i] = e[i];
  }
}

// ---------------- Global LayerNorm (two-pass), bf16 out ----------------
template<bool INBF>
__device__ __forceinline__ void ln_sum_body(const void* Xv_, float2* part, int g, int b, int t) {
  float s = 0.f, s2 = 0.f;
  if (INBF) {
    const ushortx8* Xv = (const ushortx8*)((const u16*)Xv_ + (size_t)b * (SN * DMN) + (size_t)g * 8192);
#pragma unroll
    for (int it = 0; it < 4; ++it) {
      ushortx8 x = Xv[t + it * 256];
#pragma unroll
      for (int e = 0; e < 8; ++e) { float f = bf2f(x[e]); s += f; s2 += f * f; }
    }
  } else {
    const float4* Xv = (const float4*)((const float*)Xv_ + (size_t)b * (SN * DMN) + (size_t)g * 8192);
#pragma unroll
    for (int it = 0; it < 8; ++it) {
      float4 x = Xv[t + it * 256];
      s  += x.x + x.y + x.z + x.w;
      s2 += x.x*x.x + x.y*x.y + x.z*x.z + x.w*x.w;
    }
  }
  __shared__ float rs[256], rq[256];
  rs[t] = s; rq[t] = s2;
  __syncthreads();
  for (int off = 128; off > 0; off >>= 1) {
    if (t < off) { rs[t] += rs[t + off]; rq[t] += rq[t + off]; }
    __syncthreads();
  }
  if (t == 0) part[b * 64 + g] = make_float2(rs[0], rq[0]);
}

template<bool INBF>
__device__ __forceinline__ void ln_norm_body(const void* Xv_, const float2* part,
                                             u16* Y, int g, int b, int t) {
  __shared__ float ss[64], sq[64];
  if (t < 64) { float2 p = part[b * 64 + t]; ss[t] = p.x; sq[t] = p.y; }
  __syncthreads();
  float s = 0.f, q = 0.f;
#pragma unroll
  for (int j = 0; j < 64; ++j) { s += ss[j]; q += sq[j]; }
  const float inv_n = 1.f / (float)(SN * DMN);
  const float mu = s * inv_n;
  const float var = q * inv_n - mu * mu;
  const float rstd = rsqrtf(var + 1e-5f);
  const size_t base = (size_t)b * (SN * DMN) + (size_t)g * 8192;
  if (INBF) {
    const ushortx8* Xv = (const ushortx8*)((const u16*)Xv_ + base);
#pragma unroll
    for (int it = 0; it < 4; ++it) {
      ushortx8 x = Xv[t + it * 256];
      ushortx8 o;
#pragma unroll
      for (int e = 0; e < 8; ++e) o[e] = f2bf((bf2f(x[e]) - mu) * rstd);
      *(ushortx8*)(Y + base + (size_t)(t + it * 256) * 8) = o;
    }
  } else {
    const float4* Xv = (const float4*)((const float*)Xv_ + base);
#pragma unroll
    for (int it = 0; it < 8; ++it) {
      float4 x = Xv[t + it * 256];
      ushortx4 o;
      o[0] = f2bf((x.x - mu) * rstd); o[1] = f2bf((x.y - mu) * rstd);
      o[2] = f2bf((x.z - mu) * rstd); o[3] = f2bf((x.w - mu) * rstd);
      *(ushortx4*)(Y + base + (size_t)(t + it * 256) * 4) = o;
    }
  }
}

template<bool INBF>
__global__ __launch_bounds__(256) void ln_sum(const void* __restrict__ Xv_,
                                              float2* __restrict__ part) {
  ln_sum_body<INBF>(Xv_, part, blockIdx.x, blockIdx.y, threadIdx.x);
}
template<bool INBF>
__global__ __launch_bounds__(256) void ln_norm(const void* __restrict__ Xv_,
                                               const float2* __restrict__ part,
                                               u16* __restrict__ Y) {
  ln_norm_body<INBF>(Xv_, part, Y, blockIdx.x, blockIdx.y, threadIdx.x);
}
// fused pair: z=0 bf16 src0, z=1 fp32 src1
__global__ __launch_bounds__(256) void ln_sum2(const void* __restrict__ X0,
                                               const void* __restrict__ X1,
                                               float2* __restrict__ part) {
  if (blockIdx.z == 0) ln_sum_body<true>(X0, part, blockIdx.x, blockIdx.y, threadIdx.x);
  else                 ln_sum_body<false>(X1, part + 512, blockIdx.x, blockIdx.y, threadIdx.x);
}
__global__ __launch_bounds__(256) void ln_norm2(const void* __restrict__ X0,
                                                const void* __restrict__ X1,
                                                const float2* __restrict__ part,
                                                u16* __restrict__ Y0,
                                                u16* __restrict__ Y1) {
  if (blockIdx.z == 0) ln_norm_body<true>(X0, part, Y0, blockIdx.x, blockIdx.y, threadIdx.x);
  else                 ln_norm_body<false>(X1, part + 512, Y1, blockIdx.x, blockIdx.y, threadIdx.x);
}

// ---------------- bf16 MFMA GEMM (BM x 128 tile, BK=64, 4 waves) ----------------
// BK=64 + global-source swizzle (slot ^= row&7), linear global_load_lds dest,
// matching XOR on fragment reads. DBUF: 2-phase double-buffer (one barrier/tile).
// BM in {32, 64, 128}. OMODE: 0 = fp32 out; 1 = bf16 out; 3 = QKV fused; 4 = KV
// fused. V output (seg_vt) is written in the PERMUTED slab layout that attention
// consumes directly: idx = ((((b*8+h)*16 + (s>>6))*8 + slab)*64 + d)*8 + j with
// slab = 4*(k>>5)+2*((k>>4)&1)+((k>>2)&1), j = 4*((k>>3)&1)+(k&3), k = s&63.
// RESBF: residual is bf16. QSC: scale by ATT_SC (OMODE 3: Q seg only).
template<bool RELU, bool RES, bool RESBF, int OMODE, int BM, bool QSC, bool DBUF>
__global__ __launch_bounds__(256) void gemm_mfma(const u16* __restrict__ A,
                                                 const u16* __restrict__ W,
                                                 const float* __restrict__ bias,
                                                 const void* __restrict__ resv,
                                                 void* __restrict__ Cv,
                                                 void* __restrict__ Cv2,
                                                 void* __restrict__ Cv3,
                                                 int M, int N, int K) {
  constexpr int MI = BM / 32;        // row-frags per wave (128->4, 64->2, 32->1)
  constexpr int NB = DBUF ? 2 : 1;
  __shared__ u16 As[NB][BM * 64];
  __shared__ u16 Bs[NB][128 * 64];
  const int t = threadIdx.x;
  const int lane = t & 63, w = t >> 6;
  const int wm = w >> 1, wn = w & 1;

  // T1 XCD swizzle
  const int gx = gridDim.x;
  const int lid = xcd_swz(blockIdx.y * gx + blockIdx.x, gx * gridDim.y);
  const int m0 = (lid / gx) * BM, n0 = (lid % gx) * 128;

  f32x4 acc[MI][4];
#pragma unroll
  for (int i = 0; i < MI; ++i)
#pragma unroll
    for (int j = 0; j < 4; ++j)
      acc[i][j] = (f32x4){0.f, 0.f, 0.f, 0.f};

  // staging: each round covers 32 rows (4 waves x 8 rows); thread handles 16B.
  const int srow = lane >> 3;                              // 0..7 in wave chunk
  const int scol = ((lane & 7) ^ (lane >> 3)) * 8;         // swizzled src col (elems)
  const int l15 = lane & 15, l4q = lane >> 4, l7 = lane & 7;

  auto STAGE = [&](int buf, int k0) {
#pragma unroll
    for (int c = 0; c < BM / 32; ++c) {
      const int r0 = c * 32 + w * 8;
      gload_lds16(A + (size_t)(m0 + r0 + srow) * K + k0 + scol, &As[buf][r0 * 64]);
    }
#pragma unroll
    for (int c = 0; c < 4; ++c) {
      const int r0 = c * 32 + w * 8;
      gload_lds16(W + (size_t)(n0 + r0 + srow) * K + k0 + scol, &Bs[buf][r0 * 64]);
    }
  };
  auto COMPUTE = [&](int buf) {
#pragma unroll
    for (int ks = 0; ks < 2; ++ks) {
      const int kofs = ((ks * 4 + l4q) ^ l7) * 8;          // swizzled read slot
      bf16x8 af[MI], bfr[4];
#pragma unroll
      for (int f = 0; f < MI; ++f)
        af[f]  = *(const bf16x8*)&As[buf][(wm * (BM / 2) + f * 16 + l15) * 64 + kofs];
#pragma unroll
      for (int f = 0; f < 4; ++f)
        bfr[f] = *(const bf16x8*)&Bs[buf][(wn * 64 + f * 16 + l15) * 64 + kofs];
#pragma unroll
      for (int i = 0; i < MI; ++i)
#pragma unroll
        for (int j = 0; j < 4; ++j)
          acc[i][j] = __builtin_amdgcn_mfma_f32_16x16x32_bf16(af[i], bfr[j], acc[i][j], 0, 0, 0);
    }
  };

  if (DBUF) {
    const int nt = K >> 6;
    STAGE(0, 0);
    __syncthreads();                       // drains prologue loads
    for (int ti = 0; ti < nt; ++ti) {
      if (ti + 1 < nt) STAGE((ti + 1) & 1, (ti + 1) << 6);
      COMPUTE(ti & 1);
      if (ti + 1 < nt) __syncthreads();    // drains STAGE(ti+1); protects buf reuse
    }
  } else {
    for (int k0 = 0; k0 < K; k0 += 64) {
      STAGE(0, k0);
      __syncthreads();
      COMPUTE(0);
      __syncthreads();
    }
  }

  const int crow0 = (lane >> 4) * 4;
  const int ccol  = lane & 15;
  float bv[4];
#pragma unroll
  for (int j = 0; j < 4; ++j) bv[j] = bias[n0 + wn * 64 + j * 16 + ccol];

  u16* seg_out = nullptr;
  int  seg_n0 = 0;
  bool seg_vt = false;
  if (OMODE == 3) {
    if (n0 < 512)       { seg_out = (u16*)Cv;  seg_n0 = 0; }
    else if (n0 < 1024) { seg_out = (u16*)Cv2; seg_n0 = 512; }
    else                { seg_out = (u16*)Cv3; seg_n0 = 1024; seg_vt = true; }
  } else if (OMODE == 4) {
    if (n0 < 512)       { seg_out = (u16*)Cv;  seg_n0 = 0; }
    else                { seg_out = (u16*)Cv3; seg_n0 = 512; seg_vt = true; }
  }
  const bool do_scale = QSC && (OMODE != 3 || n0 < 512);

#pragma unroll
  for (int i = 0; i < MI; ++i) {
#pragma unroll
    for (int r = 0; r < 4; ++r) {
      const int m = m0 + wm * (BM / 2) + i * 16 + crow0 + r;
#pragma unroll
      for (int j = 0; j < 4; ++j) {
        const int n = n0 + wn * 64 + j * 16 + ccol;
        float v = acc[i][j][r] + bv[j];
        if (RELU) v = fmaxf(v, 0.f);
        if (RES) {
          if (RESBF) v += bf2f(((const u16*)resv)[(size_t)m * N + n]);
          else       v += ((const float*)resv)[(size_t)m * N + n];
        }
        if (do_scale) v *= ATT_SC;
        if (OMODE == 0) {
          ((float*)Cv)[(size_t)m * N + n] = v;
        } else if (OMODE == 1) {
          ((u16*)Cv)[(size_t)m * N + n] = f2bf(v);
        } else {
          const int nn = n - seg_n0;
          if (!seg_vt) {
            seg_out[(size_t)m * 512 + nn] = f2bf(v);
          } else {
            // permuted V slab layout (consumed directly by attn staging)
            const int s_ = m & 1023, k_ = s_ & 63;
            const int slab = 4 * (k_ >> 5) + 2 * ((k_ >> 4) & 1) + ((k_ >> 2) & 1);
            const int jj   = 4 * ((k_ >> 3) & 1) + (k_ & 3);
            seg_out[(((((size_t)(m >> 10) * HN + (nn >> 6)) * 16 + (s_ >> 6)) * 8 + slab) * 64
                     + (nn & 63)) * 8 + jj] = f2bf(v);
          }
        }
      }
    }
  }
}

// ---------------- MFMA flash attention: swapped 32x32, fixed-max exp2 softmax ----
// Double-buffered K/V LDS, ONE barrier per tile. V arrives pre-permuted in slab
// layout (VTp[bh][kt][slab][d][8]) -> staging is plain 16B loads + ds_write_b128.
// NSPLIT==1: normalized O out. NSPLIT==2: raw acc + l, exact-add merge.
#define QBLK 128
#define KVB  64

template<int CAUSAL, int NSPLIT>
__global__ __launch_bounds__(256) void attn_mfma(const u16* __restrict__ Q,
                                                 const u16* __restrict__ K,
                                                 const u16* __restrict__ VTp,
                                                 u16* __restrict__ Out,
                                                 float* __restrict__ Lbuf) {
  const int lid = xcd_swz(blockIdx.y * 8 + blockIdx.x, 512);
  const int qb = lid & 7;                 // 0..7
  const int bh = lid >> 3;
  const int sp = (NSPLIT > 1) ? blockIdx.z : 0;
  const int b = bh >> 3, h = bh & 7;
  const int t = threadIdx.x;
  const int lane = t & 63, w = t >> 6;
  const int l31 = lane & 31, hi = lane >> 5;

  __shared__ __align__(16) u16 Ks[2][64 * 64];
  __shared__ __align__(16) u16 Vts[2][8 * 512];

  const int qw0 = qb * QBLK + w * 32;     // wave's first q row
  const int qglob = qw0 + l31;            // this lane's q row

  // Q B-frags (already scaled at projection)
  bf16x8 bq[4];
#pragma unroll
  for (int dk = 0; dk < 4; ++dk)
    bq[dk] = *(const bf16x8*)(Q + (size_t)(b * SN + qglob) * 512
                                + h * 64 + dk * 16 + hi * 8);

  f32x16 acc0 = {}, acc1 = {};            // O accum: D[d][q], dt=0/1
  float l_run = 0.f;                      // lane-local half-sum

  const int ntile = CAUSAL ? (2 * qb + 2) : (SN / KVB);
  const int n4 = (ntile + NSPLIT - 1) / NSPLIT;
  const int kt0 = sp * n4;
  const int ktend = (kt0 + n4 < ntile) ? (kt0 + n4) : ntile;
  const int ntk = ktend - kt0;            // block-uniform

  // staging maps
  const int srow = t >> 2;                // K row 0..63
  const int ss0  = 2 * (t & 3);           // 16B slot (0,2,4,6)
  const u16* kg0 = K + (size_t)(b * SN + srow) * 512 + h * 64 + ((ss0 ^ (srow & 7)) * 8)
                     + (size_t)kt0 * KVB * 512;
  const u16* kg1 = K + (size_t)(b * SN + srow) * 512 + h * 64 + (((ss0 + 1) ^ (srow & 7)) * 8)
                     + (size_t)kt0 * KVB * 512;
  const int vd = t & 63, vp = t >> 6;
  const u16* vg = VTp + (((size_t)bh * 16 + kt0) * 8 + 2 * vp) * 512 + vd * 8;

  ushortx8 kr0, kr1, vr0, vr1;
  auto LOADREGS = [&]() {
    kr0 = *(const ushortx8*)kg0;
    kr1 = *(const ushortx8*)kg1;
    vr0 = *(const ushortx8*)vg;
    vr1 = *(const ushortx8*)(vg + 512);
    kg0 += (size_t)KVB * 512; kg1 += (size_t)KVB * 512; vg += 4096;
  };
  auto WRITELDS = [&](int buf) {
    *(ushortx8*)&Ks[buf][t * 16]     = kr0;
    *(ushortx8*)&Ks[buf][t * 16 + 8] = kr1;
    *(ushortx8*)&Vts[buf][(2 * vp) * 512 + vd * 8]     = vr0;
    *(ushortx8*)&Vts[buf][(2 * vp + 1) * 512 + vd * 8] = vr1;
  };

  // prologue: tile0 -> buf0; prefetch tile1 regs
  LOADREGS();
  WRITELDS(0);
  if (ntk > 1) LOADREGS();
  __syncthreads();

  for (int ti = 0; ti < ntk; ++ti) {
    const int kt = kt0 + ti;
    const int k0 = kt * KVB;
    const int cur = ti & 1;
    if (ti + 1 < ntk) {
      WRITELDS(cur ^ 1);                   // regs hold tile ti+1
      if (ti + 2 < ntk) LOADREGS();        // issue tile ti+2
    }

    if (!(CAUSAL && k0 > qw0 + 31)) {
      // ---- QK^T swapped: D[k][q], accumulate over 4 dk slices ----
      f32x16 s0 = {}, s1 = {};
      __builtin_amdgcn_s_setprio(1);
#pragma unroll
      for (int dk = 0; dk < 4; ++dk) {
        const int boff = dk * 32 + hi * 16;               // byte offset in 128B row
        const int sw = boff ^ ((l31 & 7) << 4);
        bf16x8 a0 = *(const bf16x8*)&Ks[cur][l31 * 64 + (sw >> 1)];
        bf16x8 a1 = *(const bf16x8*)&Ks[cur][(32 + l31) * 64 + (sw >> 1)];
        s0 = __builtin_amdgcn_mfma_f32_32x32x16_bf16(a0, bq[dk], s0, 0, 0, 0);
        s1 = __builtin_amdgcn_mfma_f32_32x32x16_bf16(a1, bq[dk], s1, 0, 0, 0);
      }
      __builtin_amdgcn_s_setprio(0);

      // ---- fixed-max softmax: P = exp2(s) ----
      if (CAUSAL && (k0 + KVB - 1 > qw0)) {
#pragma unroll
        for (int i = 0; i < 16; ++i) {
          const int krow = (i & 3) + 8 * (i >> 2) + 4 * hi;
          if (k0 + krow > qglob)      s0[i] = -INFINITY;
          if (k0 + 32 + krow > qglob) s1[i] = -INFINITY;
        }
      }
      float ps = 0.f;
#pragma unroll
      for (int i = 0; i < 16; ++i) {
        s0[i] = exp2f(s0[i]); ps += s0[i];
        s1[i] = exp2f(s1[i]); ps += s1[i];
      }
      l_run += ps;

      // ---- PV with permuted-k slabs: B-frag = straight cvtpk pairs ----
      __builtin_amdgcn_s_setprio(1);
#pragma unroll
      for (int m = 0; m < 4; ++m) {
        uintx4 pw;
        if (m == 0) {
          pw[0] = cvtpk_bf16(s0[0], s0[1]);  pw[1] = cvtpk_bf16(s0[2], s0[3]);
          pw[2] = cvtpk_bf16(s0[4], s0[5]);  pw[3] = cvtpk_bf16(s0[6], s0[7]);
        } else if (m == 1) {
          pw[0] = cvtpk_bf16(s0[8], s0[9]);  pw[1] = cvtpk_bf16(s0[10], s0[11]);
          pw[2] = cvtpk_bf16(s0[12], s0[13]); pw[3] = cvtpk_bf16(s0[14], s0[15]);
        } else if (m == 2) {
          pw[0] = cvtpk_bf16(s1[0], s1[1]);  pw[1] = cvtpk_bf16(s1[2], s1[3]);
          pw[2] = cvtpk_bf16(s1[4], s1[5]);  pw[3] = cvtpk_bf16(s1[6], s1[7]);
        } else {
          pw[0] = cvtpk_bf16(s1[8], s1[9]);  pw[1] = cvtpk_bf16(s1[10], s1[11]);
          pw[2] = cvtpk_bf16(s1[12], s1[13]); pw[3] = cvtpk_bf16(s1[14], s1[15]);
        }
        const bf16x8 pb = *(const bf16x8*)&pw;
        const bf16x8 av0 = *(const bf16x8*)&Vts[cur][(m * 2 + hi) * 512 + l31 * 8];
        const bf16x8 av1 = *(const bf16x8*)&Vts[cur][(m * 2 + hi) * 512 + (32 + l31) * 8];
        acc0 = __builtin_amdgcn_mfma_f32_32x32x16_bf16(av0, pb, acc0, 0, 0, 0);
        acc1 = __builtin_amdgcn_mfma_f32_32x32x16_bf16(av1, pb, acc1, 0, 0, 0);
      }
      __builtin_amdgcn_s_setprio(0);
    }
    if (ti + 1 < ntk) __syncthreads();     // protects buf reuse next iter
  }

  // ---- epilogue ----
  l_run += __shfl_xor(l_run, 32);         // combine lane halves (once)
  if (NSPLIT == 1) {
    const float inv = 1.f / l_run;
    u16* op = Out + (size_t)(b * SN + qglob) * 512 + h * 64;
#pragma unroll
    for (int g = 0; g < 4; ++g) {
      ushortx4 o0, o1;
#pragma unroll
      for (int r = 0; r < 4; ++r) {
        o0[r] = f2bf(acc0[4*g + r] * inv);
        o1[r] = f2bf(acc1[4*g + r] * inv);
      }
      *(ushortx4*)(op + 4*hi + 8*g)      = o0;
      *(ushortx4*)(op + 32 + 4*hi + 8*g) = o1;
    }
  } else {
    u16* op = Out + (((size_t)(sp * 64 + bh)) * 1024 + qglob) * 64;
#pragma unroll
    for (int g = 0; g < 4; ++g) {
      ushortx4 o0, o1;
#pragma unroll
      for (int r = 0; r < 4; ++r) {
        o0[r] = f2bf(acc0[4*g + r]);
        o1[r] = f2bf(acc1[4*g + r]);
      }
      *(ushortx4*)(op + 4*hi + 8*g)      = o0;
      *(ushortx4*)(op + 32 + 4*hi + 8*g) = o1;
    }
    if (hi == 0)
      Lbuf[((size_t)(sp * 64 + bh)) * 1024 + qglob] = l_run;
  }
}

// ---------------- 2-way split merge (fixed max -> exact addition) ----------------
__global__ __launch_bounds__(256) void attn_merge2(const u16* __restrict__ Pacc,
                                                   const float* __restrict__ Lbuf,
                                                   u16* __restrict__ O) {
  const int tid = blockIdx.x * 256 + threadIdx.x;   // 524288 threads
  const int qh = tid >> 3;
  const int d0 = (tid & 7) * 8;
  const int bh = qh >> 10, q = qh & 1023;
  const int b = bh >> 3, h = bh & 7;

  const float l = Lbuf[(size_t)bh * 1024 + q] + Lbuf[(size_t)(64 + bh) * 1024 + q];
  const float inv = 1.f / l;
  ushortx8 a0 = *(const ushortx8*)(Pacc + ((size_t)bh * 1024 + q) * 64 + d0);
  ushortx8 a1 = *(const ushortx8*)(Pacc + ((size_t)(64 + bh) * 1024 + q) * 64 + d0);
  ushortx8 ov;
#pragma unroll
  for (int e = 0; e < 8; ++e)
    ov[e] = f2bf((bf2f(a0[e]) + bf2f(a1[e])) * inv);
  *(ushortx8*)(O + ((size_t)(b * 1024 + q) * 512) + h * 64 + d0) = ov;
}

extern "C" void kernel_launch(void* const* d_in, const int* in_sizes, int n_in,
                              void* d_out, int out_size, void* d_ws, size_t ws_size,
                              hipStream_t stream) {
  const float* x_enc = (const float*)d_in[0];
  const float* x_dec = (const float*)d_in[1];
  const float* mq_w = (const float*)d_in[2];  const float* mq_b = (const float*)d_in[3];
  const float* mk_w = (const float*)d_in[4];  const float* mk_b = (const float*)d_in[5];
  const float* mv_w = (const float*)d_in[6];  const float* mv_b = (const float*)d_in[7];
  const float* mo_w = (const float*)d_in[8];  const float* mo_b = (const float*)d_in[9];
  const float* cq_w = (const float*)d_in[10]; const float* cq_b = (const float*)d_in[11];
  const float* ck_w = (const float*)d_in[12]; const float* ck_b = (const float*)d_in[13];
  const float* cv_w = (const float*)d_in[14]; const float* cv_b = (const float*)d_in[15];
  const float* co_w = (const float*)d_in[16]; const float* co_b = (const float*)d_in[17];
  const float* f1_w = (const float*)d_in[18]; const float* f1_b = (const float*)d_in[19];
  const float* f2_w = (const float*)d_in[20]; const float* f2_b = (const float*)d_in[21];
  float* out = (float*)d_out;

  // ---- workspace layout (bytes) ----
  char* wsb = (char*)d_ws;
  u16* o5    = (u16*)(wsb + 0);                   // current, bf16, 8 MB
  u16* o6    = (u16*)(wsb + (16u << 20));         // result,  bf16, 8 MB
  u16* Qb    = (u16*)(wsb + (32u << 20));         // 8 MB
  u16* Kb    = (u16*)(wsb + (40u << 20));         // 8 MB
  u16* VTb   = (u16*)(wsb + (48u << 20));         // 8 MB, permuted slab layout
  u16* B0    = (u16*)(wsb + (56u << 20));         // bf16 scratch, 8 MB
  u16* B1    = (u16*)(wsb + (64u << 20));         // enc_n bf16 / attn Lbuf
  u16* FF1   = (u16*)(wsb + (72u << 20));         // FF1 32MB / attn Pacc 16MB (disjoint phases)
  u16* WB    = (u16*)(wsb + (104u << 20));        // bf16 weights, 8 MB
  float2* part = (float2*)(wsb + (112u << 20));   // LN partials (1024 float2)
  float* BC  = (float*)(wsb + (113u << 20));      // packed biases (2560 floats)

  u16* Pacc   = FF1;                              // [2][64][1024][64] bf16
  float* Lbuf = (float*)B1;                       // [2][64][1024] float

  u16* wb_mq = WB + 0 * 262144;                   // qkv fused base
  u16* wb_mo = WB + 3 * 262144;
  u16* wb_cq = WB + 4 * 262144;
  u16* wb_ck = WB + 5 * 262144;                   // kv fused base
  u16* wb_co = WB + 7 * 262144;
  u16* wb_f1 = WB + 8 * 262144; u16* wb_f2 = WB + 8 * 262144 + 1048576;

  const int M = BN * SN;  // 8192
  dim3 ln_grid(64, BN);
  dim3 ln_grid2(64, BN, 2);
  dim3 g512t(512 / 128, M / 32);     // BM=32 for N=512 GEMMs: 1024 blocks = 4/CU
  dim3 gqkv(1536 / 128, M / 64);     // BM=64: 1536 blocks = 6/CU
  dim3 gkv(1024 / 128, M / 64);      // BM=64: 1024 blocks = 4/CU
  dim3 g2048(2048 / 128, M / 128);   // BM=128: 1024 blocks
  dim3 attn_grid_c(SN / QBLK, BN * HN, 2);   // causal: 2-way KV split
  dim3 attn_grid_x(SN / QBLK, BN * HN, 1);   // cross: no split

  cvt_weights<<<4096, 256, 0, stream>>>(mq_w, mk_w, mv_w, mo_w, cq_w, ck_w, cv_w, co_w,
                                        f1_w, f2_w, WB);
  pack_bias<<<1, 256, 0, stream>>>(mq_b, mk_b, mv_b, ck_b, cv_b, BC);

  // ---- masked self-attention block ----
  ln_sum<false><<<ln_grid, 256, 0, stream>>>(x_dec, part);
  ln_norm<false><<<ln_grid, 256, 0, stream>>>(x_dec, part, B0);
  gemm_mfma<false, false, false, 3, 64, true, false><<<gqkv, 256, 0, stream>>>(
      B0, wb_mq, BC, nullptr, Qb, Kb, VTb, M, 1536, 512);
  attn_mfma<1, 2><<<attn_grid_c, 256, 0, stream>>>(Qb, Kb, VTb, Pacc, Lbuf);
  attn_merge2<<<2048, 256, 0, stream>>>(Pacc, Lbuf, B0);
  gemm_mfma<false, true, false, 1, 32, false, true><<<g512t, 256, 0, stream>>>(
      B0, wb_mo, mo_b, x_dec, o5, nullptr, nullptr, M, 512, 512);

  // ---- cross-attention block ----
  ln_sum2<<<ln_grid2, 256, 0, stream>>>(o5, x_enc, part);
  ln_norm2<<<ln_grid2, 256, 0, stream>>>(o5, x_enc, part, B0, B1);   // cur_n, enc_n
  gemm_mfma<false, false, false, 1, 32, true, true><<<g512t, 256, 0, stream>>>(
      B0, wb_cq, cq_b, nullptr, Qb, nullptr, nullptr, M, 512, 512);
  gemm_mfma<false, false, false, 4, 64, false, false><<<gkv, 256, 0, stream>>>(
      B1, wb_ck, BC + 1536, nullptr, Kb, nullptr, VTb, M, 1024, 512);
  attn_mfma<0, 1><<<attn_grid_x, 256, 0, stream>>>(Qb, Kb, VTb, B0, nullptr);
  gemm_mfma<false, true, true, 1, 32, false, true><<<g512t, 256, 0, stream>>>(
      B0, wb_co, co_b, o5, o6, nullptr, nullptr, M, 512, 512);

  // ---- feedforward block ----
  ln_sum<true><<<ln_grid, 256, 0, stream>>>(o6, part);
  ln_norm<true><<<ln_grid, 256, 0, stream>>>(o6, part, B0);      // res_n
  gemm_mfma<true, false, false, 1, 128, false, false><<<g2048, 256, 0, stream>>>(
      B0, wb_f1, f1_b, nullptr, FF1, nullptr, nullptr, M, 2048, 512);
  gemm_mfma<false, true, true, 0, 32, false, true><<<g512t, 256, 0, stream>>>(
      FF1, wb_f2, f2_b, o6, out, nullptr, nullptr, M, 512, 2048);
}